// Round 5
// baseline (213.555 us; speedup 1.0000x reference)
//
#include <hip/hip_runtime.h>
#include <stdint.h>

#define SLEN 2048
#define EMB  1024
#define NHEAD 16
#define HDIM  64
#define WINSZ 128

typedef __attribute__((ext_vector_type(8))) __bf16 bf16x8;
typedef __attribute__((ext_vector_type(4))) float  f32x4;

__device__ __forceinline__ unsigned short f2bf(float f) {
  union { float f; unsigned int u; } v;
  v.f = f;
  unsigned int r = v.u + 0x7FFFu + ((v.u >> 16) & 1u);
  return (unsigned short)(r >> 16);
}

// pack two floats to bf16 pair (round-half-up; inputs finite, in [0,1] for P)
__device__ __forceinline__ unsigned int pack_bf(float a, float b) {
  union { float f; unsigned int u; } x, y;
  x.f = a; y.f = b;
  return ((y.u + 0x8000u) & 0xFFFF0000u) | ((x.u + 0x8000u) >> 16);
}

// One fused convert for x, w_in, w_out -> contiguous bf16 region at ws base.
__global__ void cvt_all(const float* __restrict__ x,
                        const float* __restrict__ wi,
                        const float* __restrict__ wo,
                        unsigned short* __restrict__ dst) {
  const long n0 = 8388608, n1 = n0 + 3145728, n2 = n1 + 1048576;
  long i = ((long)blockIdx.x * 256 + threadIdx.x) * 4;
  if (i >= n2) return;
  const float* src; long off;
  if (i < n0)      { src = x;  off = i; }
  else if (i < n1) { src = wi; off = i - n0; }
  else             { src = wo; off = i - n1; }
  float4 f = *(const float4*)(src + off);
  ushort4 o;
  o.x = f2bf(f.x); o.y = f2bf(f.y); o.z = f2bf(f.z); o.w = f2bf(f.w);
  *(ushort4*)(dst + i) = o;
}

#define AS1(p) (const __attribute__((address_space(1))) unsigned int*)((const void*)(p))
#define AS3(p) (__attribute__((address_space(3))) unsigned int*)((void*)(p))

// C = A[M,K] * B[N,K]^T + bias.  MODE 0: fp32 out at ldc.  MODE 1 (qkv):
// cols <2048 -> bf16 at row-stride 2048; cols >=2048 (V) -> transposed into
// vt[b][h][d][s] bf16.
template <int MODE>
__global__ __launch_bounds__(256, 2) void gemm_nt(
    const unsigned short* __restrict__ A,
    const unsigned short* __restrict__ B,
    const float* __restrict__ bias,
    void* __restrict__ Cout,
    unsigned short* __restrict__ vt,
    int M, int N, int K, int ldc)
{
  __shared__ unsigned short As[128 * 64];
  __shared__ unsigned short Bs[128 * 64];
  const int tid  = threadIdx.x;
  const int wave = tid >> 6, lane = tid & 63;
  const int quad = lane >> 4, l16 = lane & 15;
  const int wm = (wave >> 1) * 64, wn = (wave & 1) * 64;
  const long mBase = (long)blockIdx.y * 128;
  const long nBase = (long)blockIdx.x * 128;
  const int lr  = lane >> 3;
  const int lks = ((lane & 7) ^ lr) * 8;
  const int swz = l16 & 7;

  f32x4 acc[4][4];
#pragma unroll
  for (int i = 0; i < 4; ++i)
#pragma unroll
    for (int j = 0; j < 4; ++j)
#pragma unroll
      for (int r = 0; r < 4; ++r) acc[i][j][r] = 0.f;

  for (int k0 = 0; k0 < K; k0 += 64) {
    __syncthreads();
#pragma unroll
    for (int t = 0; t < 4; ++t) {
      const int r0 = (wave * 4 + t) * 8;
      const unsigned short* ga = A + (mBase + r0 + lr) * (long)K + k0 + lks;
      __builtin_amdgcn_global_load_lds(AS1(ga), AS3(As + r0 * 64), 16, 0, 0);
      const unsigned short* gb = B + (nBase + r0 + lr) * (long)K + k0 + lks;
      __builtin_amdgcn_global_load_lds(AS1(gb), AS3(Bs + r0 * 64), 16, 0, 0);
    }
    __syncthreads();

#pragma unroll
    for (int s = 0; s < 2; ++s) {
      bf16x8 aF[4], bF[4];
#pragma unroll
      for (int i = 0; i < 4; ++i)
        aF[i] = *(const bf16x8*)(As + (wm + i * 16 + l16) * 64 + (((s * 4 + quad) ^ swz) * 8));
#pragma unroll
      for (int j = 0; j < 4; ++j)
        bF[j] = *(const bf16x8*)(Bs + (wn + j * 16 + l16) * 64 + (((s * 4 + quad) ^ swz) * 8));
#pragma unroll
      for (int i = 0; i < 4; ++i)
#pragma unroll
        for (int j = 0; j < 4; ++j)
          acc[i][j] = __builtin_amdgcn_mfma_f32_16x16x32_bf16(aF[i], bF[j], acc[i][j], 0, 0, 0);
    }
  }

  if (MODE == 1 && nBase >= 2048) {
    // V block: write transposed into vt[b][h][d][s]
#pragma unroll
    for (int j = 0; j < 4; ++j) {
      const int nG = (int)nBase + wn + j * 16 + l16;
      const float bv = bias[nG];
      const int hd = nG - 2048;
      const int hh = hd >> 6, dd = hd & 63;
#pragma unroll
      for (int i = 0; i < 4; ++i)
#pragma unroll
        for (int r = 0; r < 4; ++r) {
          const int mG = (int)mBase + wm + i * 16 + quad * 4 + r;
          const int bb = mG >> 11, ss = mG & 2047;
          vt[(((long)(bb * NHEAD + hh)) * HDIM + dd) * SLEN + ss] = f2bf(acc[i][j][r] + bv);
        }
    }
  } else {
#pragma unroll
    for (int j = 0; j < 4; ++j) {
      const long nG = nBase + wn + j * 16 + l16;
      const float bv = bias[nG];
#pragma unroll
      for (int i = 0; i < 4; ++i)
#pragma unroll
        for (int r = 0; r < 4; ++r) {
          const long mG = mBase + wm + i * 16 + quad * 4 + r;
          const float v = acc[i][j][r] + bv;
          if (MODE == 1) ((unsigned short*)Cout)[mG * ldc + nG] = f2bf(v);
          else           ((float*)Cout)[mG * ldc + nG] = v;
        }
    }
  }
}

// Banded-causal flash attention, S^T orientation, batched softmax.
// qk: [B*S][2048] bf16 (Q cols 0..1023, K cols 1024..2047), vT: [B*H][64][2048].
// V is read directly from global (L2-resident window); only K is staged in LDS.
__global__ __launch_bounds__(256, 4) void local_attn(
    const unsigned short* __restrict__ qk,
    const unsigned short* __restrict__ vT,
    unsigned short* __restrict__ outw)
{
  const int qb = blockIdx.x;   // 64-query tile
  const int h  = blockIdx.y;
  const int b  = blockIdx.z;
  const int tid = threadIdx.x;
  const int wave = tid >> 6, lane = tid & 63;
  const int quad = lane >> 4, l16 = lane & 15;

  __shared__ unsigned short Klds[192 * 64];   // [key][chunk^(key&7)] swizzled

  const int kwin0 = qb * 64 - WINSZ;          // global key of local key 0

  // --- K staging via global_load_lds (swizzled, clamped rows) ---
  {
    const int kr = lane >> 3, kc = lane & 7;
    const long colOff = 1024 + h * HDIM + ((kc ^ kr) * 8);
#pragma unroll
    for (int t = 0; t < 6; ++t) {
      const int u = wave * 6 + t;                 // unit of 8 keys
      const int sk = max(kwin0 + u * 8 + kr, 0);  // clamp; junk rows masked later
      const unsigned short* g = qk + (long)(b * SLEN + sk) * 2048 + colOff;
      __builtin_amdgcn_global_load_lds(AS1(g), AS3(Klds + u * 512), 16, 0, 0);
    }
  }

  // Q fragments (B-operand): 16 queries per wave
  const int q0 = qb * 64 + wave * 16;
  const long qrow = (long)(b * SLEN + q0 + l16) * 2048 + h * HDIM;
  const bf16x8 qB0 = *(const bf16x8*)(qk + qrow + quad * 8);
  const bf16x8 qB1 = *(const bf16x8*)(qk + qrow + 32 + quad * 8);

  const unsigned short* vbase = vT + ((long)(b * NHEAD + h)) * HDIM * SLEN;

  __syncthreads();

  // --- QK^T (S^T orientation): all 5 x 32 keys ---
  const int lbase = (wave * 16) & ~31;
  const int kx = l16 & 7;
  const int a0 = (quad ^ kx) * 8;
  const int a1 = ((4 + quad) ^ kx) * 8;
  f32x4 sc[5][2];
#pragma unroll
  for (int it = 0; it < 5; ++it) {
    const int l0 = lbase + it * 32;
#pragma unroll
    for (int half = 0; half < 2; ++half) {
      const unsigned short* kr_ = Klds + (l0 + half * 16 + l16) * 64;
      const bf16x8 kA0 = *(const bf16x8*)(kr_ + a0);
      const bf16x8 kA1 = *(const bf16x8*)(kr_ + a1);
      f32x4 s;
#pragma unroll
      for (int r = 0; r < 4; ++r) s[r] = 0.f;
      s = __builtin_amdgcn_mfma_f32_16x16x32_bf16(kA0, qB0, s, 0, 0, 0);
      s = __builtin_amdgcn_mfma_f32_16x16x32_bf16(kA1, qB1, s, 0, 0, 0);
      sc[it][half] = s;   // row = key_local = quad*4+r, col = query = l16
    }
  }

  // --- mask + scale; batched softmax (reduce over quads: 2 shfl steps) ---
  // Valid local keys for query qlocal: [qlocal - WINSZ, qlocal], further
  // clipped below -kwin0 (clamped staging rows are junk whenever kwin0 < 0).
  const int qlocal = WINSZ + wave * 16 + l16;       // own query, local coords
  const int lo = max(wave * 16 + l16, kwin0 < 0 ? -kwin0 : 0);
  const int kb = lbase + quad * 4;
  float m = -3.0e38f;
#pragma unroll
  for (int it = 0; it < 5; ++it)
#pragma unroll
    for (int half = 0; half < 2; ++half)
#pragma unroll
      for (int r = 0; r < 4; ++r) {
        const int kl = kb + it * 32 + half * 16 + r;
        float v = sc[it][half][r] * 0.125f;
        v = (kl >= lo && kl <= qlocal) ? v : -3.0e38f;
        sc[it][half][r] = v;
        m = fmaxf(m, v);
      }
  m = fmaxf(m, __shfl_xor(m, 16, 64));
  m = fmaxf(m, __shfl_xor(m, 32, 64));

  float lsum = 0.f;
#pragma unroll
  for (int it = 0; it < 5; ++it)
#pragma unroll
    for (int half = 0; half < 2; ++half)
#pragma unroll
      for (int r = 0; r < 4; ++r) {
        const float e = __expf(sc[it][half][r] - m);
        sc[it][half][r] = e;
        lsum += e;
      }
  lsum += __shfl_xor(lsum, 16, 64);
  lsum += __shfl_xor(lsum, 32, 64);
  const float invl = 1.0f / lsum;

  // --- PV: O^T = V^T * P^T; P^T B-frag assembled via shuffles; V from global ---
  f32x4 Oacc[4];
#pragma unroll
  for (int dt = 0; dt < 4; ++dt)
#pragma unroll
    for (int r = 0; r < 4; ++r) Oacc[dt][r] = 0.f;

#pragma unroll
  for (int it = 0; it < 5; ++it) {
    const int l0 = lbase + it * 32;
    // pack this lane's 8 P values (4 per half) into bf16 pairs
    const unsigned int u0 = pack_bf(sc[it][0][0], sc[it][0][1]);
    const unsigned int u1 = pack_bf(sc[it][0][2], sc[it][0][3]);
    const unsigned int u2 = pack_bf(sc[it][1][0], sc[it][1][1]);
    const unsigned int u3 = pack_bf(sc[it][1][2], sc[it][1][3]);
    // gather B-frag: lane needs keys quad*8 + [0..7] of query l16
    unsigned int breg[4];
#pragma unroll
    for (int r = 0; r < 4; ++r) {
      const int srcl = ((quad & 1) * 2 + (r >> 1)) * 16 + l16;
      const unsigned int ga = __shfl((int)((r & 1) ? u1 : u0), srcl, 64);
      const unsigned int gb = __shfl((int)((r & 1) ? u3 : u2), srcl, 64);
      breg[r] = (quad >> 1) ? gb : ga;
    }
    union { unsigned int u[4]; bf16x8 v; } pB;
    pB.u[0] = breg[0]; pB.u[1] = breg[1]; pB.u[2] = breg[2]; pB.u[3] = breg[3];

    const int col = max(kwin0 + l0 + quad * 8, 0);  // junk cols hit P=0
#pragma unroll
    for (int dt = 0; dt < 4; ++dt) {
      const bf16x8 vA = *(const bf16x8*)(vbase + (long)(dt * 16 + l16) * SLEN + col);
      Oacc[dt] = __builtin_amdgcn_mfma_f32_16x16x32_bf16(vA, pB.v, Oacc[dt], 0, 0, 0);
    }
  }

  // --- epilogue: O^T C-layout (row = d_local = quad*4+r, col = q = l16) ---
  const long obase = (long)(b * SLEN + q0 + l16) * EMB + h * HDIM;
#pragma unroll
  for (int dt = 0; dt < 4; ++dt)
#pragma unroll
    for (int r = 0; r < 4; ++r)
      outw[obase + dt * 16 + quad * 4 + r] = f2bf(Oacc[dt][r] * invl);
}

extern "C" void kernel_launch(void* const* d_in, const int* in_sizes, int n_in,
                              void* d_out, int out_size, void* d_ws, size_t ws_size,
                              hipStream_t stream) {
  const float* x     = (const float*)d_in[0];
  const float* w_in  = (const float*)d_in[1];
  const float* b_in  = (const float*)d_in[2];
  const float* w_out = (const float*)d_in[3];
  const float* b_out = (const float*)d_in[4];
  float* out = (float*)d_out;

  char* ws = (char*)d_ws;
  unsigned short* xb    = (unsigned short*)(ws + 0);          // 16,777,216
  unsigned short* winb  = (unsigned short*)(ws + 16777216);   //  6,291,456
  unsigned short* woutb = (unsigned short*)(ws + 23068672);   //  2,097,152
  unsigned short* qkb   = (unsigned short*)(ws + 25165824);   // 8192x2048 bf16 = 33,554,432
  unsigned short* attn  = (unsigned short*)(ws + 58720256);   // 16,777,216
  unsigned short* vT    = (unsigned short*)(ws + 75497472);   // 16,777,216  (total 92,274,688)

  // fused converts: dst regions are contiguous (xb|winb|woutb)
  const long ncv = 8388608 + 3145728 + 1048576;               // 12,582,912
  cvt_all<<<(int)(ncv / 1024), 256, 0, stream>>>(x, w_in, w_out, xb);

  // qkv projection: Q,K -> qkb (stride 2048); V -> vT transposed
  gemm_nt<1><<<dim3(3072 / 128, 8192 / 128), 256, 0, stream>>>(
      xb, winb, b_in, (void*)qkb, vT, 8192, 3072, 1024, 2048);

  local_attn<<<dim3(SLEN / 64, NHEAD, 4), 256, 0, stream>>>(qkb, vT, attn);

  gemm_nt<0><<<dim3(1024 / 128, 8192 / 128), 256, 0, stream>>>(
      attn, woutb, b_out, (void*)out, nullptr, 8192, 1024, 1024, 1024);
}

// Round 6
// 204.990 us; speedup vs baseline: 1.0418x; 1.0418x over previous
//
#include <hip/hip_runtime.h>
#include <stdint.h>

#define SLEN 2048
#define EMB  1024
#define NHEAD 16
#define HDIM  64
#define WINSZ 128

typedef __attribute__((ext_vector_type(8))) __bf16 bf16x8;
typedef __attribute__((ext_vector_type(4))) float  f32x4;

__device__ __forceinline__ unsigned short f2bf(float f) {
  union { float f; unsigned int u; } v;
  v.f = f;
  unsigned int r = v.u + 0x7FFFu + ((v.u >> 16) & 1u);
  return (unsigned short)(r >> 16);
}

// pack two floats to bf16 pair (round-half-up; inputs finite, in [0,1] for P)
__device__ __forceinline__ unsigned int pack_bf(float a, float b) {
  union { float f; unsigned int u; } x, y;
  x.f = a; y.f = b;
  return ((y.u + 0x8000u) & 0xFFFF0000u) | ((x.u + 0x8000u) >> 16);
}

// One fused convert for x, w_in, w_out -> contiguous bf16 region at ws base.
__global__ void cvt_all(const float* __restrict__ x,
                        const float* __restrict__ wi,
                        const float* __restrict__ wo,
                        unsigned short* __restrict__ dst) {
  const long n0 = 8388608, n1 = n0 + 3145728, n2 = n1 + 1048576;
  long i = ((long)blockIdx.x * 256 + threadIdx.x) * 4;
  if (i >= n2) return;
  const float* src; long off;
  if (i < n0)      { src = x;  off = i; }
  else if (i < n1) { src = wi; off = i - n0; }
  else             { src = wo; off = i - n1; }
  float4 f = *(const float4*)(src + off);
  ushort4 o;
  o.x = f2bf(f.x); o.y = f2bf(f.y); o.z = f2bf(f.z); o.w = f2bf(f.w);
  *(ushort4*)(dst + i) = o;
}

#define AS1(p) (const __attribute__((address_space(1))) unsigned int*)((const void*)(p))
#define AS3(p) (__attribute__((address_space(3))) unsigned int*)((void*)(p))

// C = A[M,K] * B[N,K]^T + bias.  MODE 0: fp32 out at ldc.  MODE 1 (qkv):
// cols <2048 -> bf16 at row-stride 2048; cols >=2048 (V) -> transposed into
// vt[b][h][d][s] bf16 (packed ushort4 stores along s).
template <int MODE>
__global__ __launch_bounds__(256, 2) void gemm_nt(
    const unsigned short* __restrict__ A,
    const unsigned short* __restrict__ B,
    const float* __restrict__ bias,
    void* __restrict__ Cout,
    unsigned short* __restrict__ vt,
    int M, int N, int K, int ldc)
{
  __shared__ unsigned short As[128 * 64];
  __shared__ unsigned short Bs[128 * 64];
  const int tid  = threadIdx.x;
  const int wave = tid >> 6, lane = tid & 63;
  const int quad = lane >> 4, l16 = lane & 15;
  const int wm = (wave >> 1) * 64, wn = (wave & 1) * 64;
  const long mBase = (long)blockIdx.y * 128;
  const long nBase = (long)blockIdx.x * 128;
  const int lr  = lane >> 3;
  const int lks = ((lane & 7) ^ lr) * 8;
  const int swz = l16 & 7;

  f32x4 acc[4][4];
#pragma unroll
  for (int i = 0; i < 4; ++i)
#pragma unroll
    for (int j = 0; j < 4; ++j)
#pragma unroll
      for (int r = 0; r < 4; ++r) acc[i][j][r] = 0.f;

  for (int k0 = 0; k0 < K; k0 += 64) {
    __syncthreads();
#pragma unroll
    for (int t = 0; t < 4; ++t) {
      const int r0 = (wave * 4 + t) * 8;
      const unsigned short* ga = A + (mBase + r0 + lr) * (long)K + k0 + lks;
      __builtin_amdgcn_global_load_lds(AS1(ga), AS3(As + r0 * 64), 16, 0, 0);
      const unsigned short* gb = B + (nBase + r0 + lr) * (long)K + k0 + lks;
      __builtin_amdgcn_global_load_lds(AS1(gb), AS3(Bs + r0 * 64), 16, 0, 0);
    }
    __syncthreads();

#pragma unroll
    for (int s = 0; s < 2; ++s) {
      bf16x8 aF[4], bF[4];
#pragma unroll
      for (int i = 0; i < 4; ++i)
        aF[i] = *(const bf16x8*)(As + (wm + i * 16 + l16) * 64 + (((s * 4 + quad) ^ swz) * 8));
#pragma unroll
      for (int j = 0; j < 4; ++j)
        bF[j] = *(const bf16x8*)(Bs + (wn + j * 16 + l16) * 64 + (((s * 4 + quad) ^ swz) * 8));
#pragma unroll
      for (int i = 0; i < 4; ++i)
#pragma unroll
        for (int j = 0; j < 4; ++j)
          acc[i][j] = __builtin_amdgcn_mfma_f32_16x16x32_bf16(aF[i], bF[j], acc[i][j], 0, 0, 0);
    }
  }

  if (MODE == 1 && nBase >= 2048) {
    // V block: write transposed into vt[b][h][d][s]; r=0..3 -> s contiguous
#pragma unroll
    for (int j = 0; j < 4; ++j) {
      const int nG = (int)nBase + wn + j * 16 + l16;
      const float bv = bias[nG];
      const int hd = nG - 2048;
      const int hh = hd >> 6, dd = hd & 63;
#pragma unroll
      for (int i = 0; i < 4; ++i) {
        const int mG0 = (int)mBase + wm + i * 16 + quad * 4;
        const int bb = mG0 >> 11, ss = mG0 & 2047;
        ushort4 o;
        o.x = f2bf(acc[i][j][0] + bv);
        o.y = f2bf(acc[i][j][1] + bv);
        o.z = f2bf(acc[i][j][2] + bv);
        o.w = f2bf(acc[i][j][3] + bv);
        *(ushort4*)(vt + (((long)(bb * NHEAD + hh)) * HDIM + dd) * SLEN + ss) = o;
      }
    }
  } else {
#pragma unroll
    for (int j = 0; j < 4; ++j) {
      const long nG = nBase + wn + j * 16 + l16;
      const float bv = bias[nG];
#pragma unroll
      for (int i = 0; i < 4; ++i)
#pragma unroll
        for (int r = 0; r < 4; ++r) {
          const long mG = mBase + wm + i * 16 + quad * 4 + r;
          const float v = acc[i][j][r] + bv;
          if (MODE == 1) ((unsigned short*)Cout)[mG * ldc + nG] = f2bf(v);
          else           ((float*)Cout)[mG * ldc + nG] = v;
        }
    }
  }
}

// Banded-causal flash attention, S^T orientation, batched softmax.
// qk: [B*S][2048] bf16 (Q cols 0..1023, K cols 1024..2047), vT: [B*H][64][2048].
__global__ __launch_bounds__(256, 3) void local_attn(
    const unsigned short* __restrict__ qk,
    const unsigned short* __restrict__ vT,
    unsigned short* __restrict__ outw)
{
  const int qb = blockIdx.x;   // 64-query tile
  const int h  = blockIdx.y;
  const int b  = blockIdx.z;
  const int tid = threadIdx.x;
  const int wave = tid >> 6, lane = tid & 63;
  const int quad = lane >> 4, l16 = lane & 15;

  __shared__ unsigned short Klds[192 * 64];   // [key][chunk^(key&7)] swizzled
  __shared__ unsigned short Vlds[64 * 200];   // [d][key] stride 200

  const int kwin0 = qb * 64 - WINSZ;          // global key of local key 0

  // --- K staging via global_load_lds (swizzled, clamped rows) ---
  {
    const int kr = lane >> 3, kc = lane & 7;
    const long colOff = 1024 + h * HDIM + ((kc ^ kr) * 8);
#pragma unroll
    for (int t = 0; t < 6; ++t) {
      const int u = wave * 6 + t;                 // unit of 8 keys
      const int sk = max(kwin0 + u * 8 + kr, 0);  // clamp; junk rows masked later
      const unsigned short* g = qk + (long)(b * SLEN + sk) * 2048 + colOff;
      __builtin_amdgcn_global_load_lds(AS1(g), AS3(Klds + u * 512), 16, 0, 0);
    }
  }
  // --- V^T staging: coalesced reads from vT, key-contiguous LDS writes ---
  {
    const unsigned short* vbase = vT + ((long)(b * NHEAD + h)) * HDIM * SLEN;
#pragma unroll
    for (int t = 0; t < 8; ++t) {
      const int c = t * 256 + tid;
      const int d = c >> 5, k8 = c & 31;
      if (k8 < 24) {
        const int s0 = max(kwin0 + k8 * 8, 0);
        uint4 v = *(const uint4*)(vbase + (long)d * SLEN + s0);
        *(uint4*)(Vlds + d * 200 + k8 * 8) = v;
      }
    }
  }

  // Q fragments (B-operand): 16 queries per wave
  const int q0 = qb * 64 + wave * 16;
  const long qrow = (long)(b * SLEN + q0 + l16) * 2048 + h * HDIM;
  const bf16x8 qB0 = *(const bf16x8*)(qk + qrow + quad * 8);
  const bf16x8 qB1 = *(const bf16x8*)(qk + qrow + 32 + quad * 8);

  __syncthreads();

  // --- QK^T (S^T orientation): all 5 x 32 keys ---
  const int lbase = (wave * 16) & ~31;
  const int kx = l16 & 7;
  const int a0 = (quad ^ kx) * 8;
  const int a1 = ((4 + quad) ^ kx) * 8;
  f32x4 sc[5][2];
#pragma unroll
  for (int it = 0; it < 5; ++it) {
    const int l0 = lbase + it * 32;
#pragma unroll
    for (int half = 0; half < 2; ++half) {
      const unsigned short* kr_ = Klds + (l0 + half * 16 + l16) * 64;
      const bf16x8 kA0 = *(const bf16x8*)(kr_ + a0);
      const bf16x8 kA1 = *(const bf16x8*)(kr_ + a1);
      f32x4 s;
#pragma unroll
      for (int r = 0; r < 4; ++r) s[r] = 0.f;
      s = __builtin_amdgcn_mfma_f32_16x16x32_bf16(kA0, qB0, s, 0, 0, 0);
      s = __builtin_amdgcn_mfma_f32_16x16x32_bf16(kA1, qB1, s, 0, 0, 0);
      sc[it][half] = s;   // row = key_local = quad*4+r, col = query = l16
    }
  }

  // --- mask + scale; batched softmax (reduce over quads: 2 shfl steps) ---
  const int qlocal = WINSZ + wave * 16 + l16;       // own query, local coords
  const int lo = max(wave * 16 + l16, kwin0 < 0 ? -kwin0 : 0);
  const int kb = lbase + quad * 4;
  float m = -3.0e38f;
#pragma unroll
  for (int it = 0; it < 5; ++it)
#pragma unroll
    for (int half = 0; half < 2; ++half)
#pragma unroll
      for (int r = 0; r < 4; ++r) {
        const int kl = kb + it * 32 + half * 16 + r;
        float v = sc[it][half][r] * 0.125f;
        v = (kl >= lo && kl <= qlocal) ? v : -3.0e38f;
        sc[it][half][r] = v;
        m = fmaxf(m, v);
      }
  m = fmaxf(m, __shfl_xor(m, 16, 64));
  m = fmaxf(m, __shfl_xor(m, 32, 64));

  float lsum = 0.f;
#pragma unroll
  for (int it = 0; it < 5; ++it)
#pragma unroll
    for (int half = 0; half < 2; ++half)
#pragma unroll
      for (int r = 0; r < 4; ++r) {
        const float e = __expf(sc[it][half][r] - m);
        sc[it][half][r] = e;
        lsum += e;
      }
  lsum += __shfl_xor(lsum, 16, 64);
  lsum += __shfl_xor(lsum, 32, 64);
  const float invl = 1.0f / lsum;

  // --- PV: O^T = V^T * P^T; P^T B-frag assembled via shuffles ---
  f32x4 Oacc[4];
#pragma unroll
  for (int dt = 0; dt < 4; ++dt)
#pragma unroll
    for (int r = 0; r < 4; ++r) Oacc[dt][r] = 0.f;

#pragma unroll
  for (int it = 0; it < 5; ++it) {
    const int l0 = lbase + it * 32;
    // pack this lane's 8 P values (4 per half) into bf16 pairs
    const unsigned int u0 = pack_bf(sc[it][0][0], sc[it][0][1]);
    const unsigned int u1 = pack_bf(sc[it][0][2], sc[it][0][3]);
    const unsigned int u2 = pack_bf(sc[it][1][0], sc[it][1][1]);
    const unsigned int u3 = pack_bf(sc[it][1][2], sc[it][1][3]);
    // gather B-frag: lane needs keys quad*8 + [0..7] of query l16
    unsigned int breg[4];
#pragma unroll
    for (int r = 0; r < 4; ++r) {
      const int srcl = ((quad & 1) * 2 + (r >> 1)) * 16 + l16;
      const unsigned int ga = __shfl((int)((r & 1) ? u1 : u0), srcl, 64);
      const unsigned int gb = __shfl((int)((r & 1) ? u3 : u2), srcl, 64);
      breg[r] = (quad >> 1) ? gb : ga;
    }
    union { unsigned int u[4]; bf16x8 v; } pB;
    pB.u[0] = breg[0]; pB.u[1] = breg[1]; pB.u[2] = breg[2]; pB.u[3] = breg[3];
#pragma unroll
    for (int dt = 0; dt < 4; ++dt) {
      const bf16x8 vA = *(const bf16x8*)(Vlds + (dt * 16 + l16) * 200 + l0 + quad * 8);
      Oacc[dt] = __builtin_amdgcn_mfma_f32_16x16x32_bf16(vA, pB.v, Oacc[dt], 0, 0, 0);
    }
  }

  // --- epilogue: O^T C-layout; r=0..3 contiguous -> packed ushort4 stores ---
  const long obase = (long)(b * SLEN + q0 + l16) * EMB + h * HDIM;
#pragma unroll
  for (int dt = 0; dt < 4; ++dt) {
    ushort4 o;
    o.x = f2bf(Oacc[dt][0] * invl);
    o.y = f2bf(Oacc[dt][1] * invl);
    o.z = f2bf(Oacc[dt][2] * invl);
    o.w = f2bf(Oacc[dt][3] * invl);
    *(ushort4*)(outw + obase + dt * 16 + quad * 4) = o;
  }
}

extern "C" void kernel_launch(void* const* d_in, const int* in_sizes, int n_in,
                              void* d_out, int out_size, void* d_ws, size_t ws_size,
                              hipStream_t stream) {
  const float* x     = (const float*)d_in[0];
  const float* w_in  = (const float*)d_in[1];
  const float* b_in  = (const float*)d_in[2];
  const float* w_out = (const float*)d_in[3];
  const float* b_out = (const float*)d_in[4];
  float* out = (float*)d_out;

  char* ws = (char*)d_ws;
  unsigned short* xb    = (unsigned short*)(ws + 0);          // 16,777,216
  unsigned short* winb  = (unsigned short*)(ws + 16777216);   //  6,291,456
  unsigned short* woutb = (unsigned short*)(ws + 23068672);   //  2,097,152
  unsigned short* qkb   = (unsigned short*)(ws + 25165824);   // 8192x2048 bf16 = 33,554,432
  unsigned short* attn  = (unsigned short*)(ws + 58720256);   // 16,777,216
  unsigned short* vT    = (unsigned short*)(ws + 75497472);   // 16,777,216  (total 92,274,688)

  // fused converts: dst regions are contiguous (xb|winb|woutb)
  const long ncv = 8388608 + 3145728 + 1048576;               // 12,582,912
  cvt_all<<<(int)(ncv / 1024), 256, 0, stream>>>(x, w_in, w_out, xb);

  // qkv projection: Q,K -> qkb (stride 2048); V -> vT transposed
  gemm_nt<1><<<dim3(3072 / 128, 8192 / 128), 256, 0, stream>>>(
      xb, winb, b_in, (void*)qkb, vT, 8192, 3072, 1024, 2048);

  local_attn<<<dim3(SLEN / 64, NHEAD, 4), 256, 0, stream>>>(qkb, vT, attn);

  gemm_nt<0><<<dim3(1024 / 128, 8192 / 128), 256, 0, stream>>>(
      attn, woutb, b_out, (void*)out, nullptr, 8192, 1024, 1024, 1024);
}

// Round 7
// 202.954 us; speedup vs baseline: 1.0522x; 1.0100x over previous
//
#include <hip/hip_runtime.h>
#include <stdint.h>

#define SLEN 2048
#define EMB  1024
#define NHEAD 16
#define HDIM  64
#define WINSZ 128

typedef __attribute__((ext_vector_type(8))) __bf16 bf16x8;
typedef __attribute__((ext_vector_type(4))) float  f32x4;

__device__ __forceinline__ unsigned short f2bf(float f) {
  union { float f; unsigned int u; } v;
  v.f = f;
  unsigned int r = v.u + 0x7FFFu + ((v.u >> 16) & 1u);
  return (unsigned short)(r >> 16);
}

// pack two floats to bf16 pair (round-half-up; inputs finite, in [0,1] for P)
__device__ __forceinline__ unsigned int pack_bf(float a, float b) {
  union { float f; unsigned int u; } x, y;
  x.f = a; y.f = b;
  return ((y.u + 0x8000u) & 0xFFFF0000u) | ((x.u + 0x8000u) >> 16);
}

// One fused convert for x, w_in, w_out -> contiguous bf16 region at ws base.
__global__ void cvt_all(const float* __restrict__ x,
                        const float* __restrict__ wi,
                        const float* __restrict__ wo,
                        unsigned short* __restrict__ dst) {
  const long n0 = 8388608, n1 = n0 + 3145728, n2 = n1 + 1048576;
  long i = ((long)blockIdx.x * 256 + threadIdx.x) * 4;
  if (i >= n2) return;
  const float* src; long off;
  if (i < n0)      { src = x;  off = i; }
  else if (i < n1) { src = wi; off = i - n0; }
  else             { src = wo; off = i - n1; }
  float4 f = *(const float4*)(src + off);
  ushort4 o;
  o.x = f2bf(f.x); o.y = f2bf(f.y); o.z = f2bf(f.z); o.w = f2bf(f.w);
  *(ushort4*)(dst + i) = o;
}

#define AS1(p) (const __attribute__((address_space(1))) unsigned int*)((const void*)(p))
#define AS3(p) (__attribute__((address_space(3))) unsigned int*)((void*)(p))

// C = A[M,K] * B[N,K]^T + bias.  MODE 0: fp32 out at ldc.  MODE 1 (qkv):
// cols <2048 -> bf16 at row-stride 2048; cols >=2048 (V) -> transposed into
// vt[b][h][d][s] bf16 (packed ushort4 stores along s).
template <int MODE>
__global__ __launch_bounds__(256, 2) void gemm_nt(
    const unsigned short* __restrict__ A,
    const unsigned short* __restrict__ B,
    const float* __restrict__ bias,
    void* __restrict__ Cout,
    unsigned short* __restrict__ vt,
    int M, int N, int K, int ldc)
{
  __shared__ unsigned short As[128 * 64];
  __shared__ unsigned short Bs[128 * 64];
  const int tid  = threadIdx.x;
  const int wave = tid >> 6, lane = tid & 63;
  const int quad = lane >> 4, l16 = lane & 15;
  const int wm = (wave >> 1) * 64, wn = (wave & 1) * 64;
  const long mBase = (long)blockIdx.y * 128;
  const long nBase = (long)blockIdx.x * 128;
  const int lr  = lane >> 3;
  const int lks = ((lane & 7) ^ lr) * 8;
  const int swz = l16 & 7;

  f32x4 acc[4][4];
#pragma unroll
  for (int i = 0; i < 4; ++i)
#pragma unroll
    for (int j = 0; j < 4; ++j)
#pragma unroll
      for (int r = 0; r < 4; ++r) acc[i][j][r] = 0.f;

  for (int k0 = 0; k0 < K; k0 += 64) {
    __syncthreads();
#pragma unroll
    for (int t = 0; t < 4; ++t) {
      const int r0 = (wave * 4 + t) * 8;
      const unsigned short* ga = A + (mBase + r0 + lr) * (long)K + k0 + lks;
      __builtin_amdgcn_global_load_lds(AS1(ga), AS3(As + r0 * 64), 16, 0, 0);
      const unsigned short* gb = B + (nBase + r0 + lr) * (long)K + k0 + lks;
      __builtin_amdgcn_global_load_lds(AS1(gb), AS3(Bs + r0 * 64), 16, 0, 0);
    }
    __syncthreads();

#pragma unroll
    for (int s = 0; s < 2; ++s) {
      bf16x8 aF[4], bF[4];
#pragma unroll
      for (int i = 0; i < 4; ++i)
        aF[i] = *(const bf16x8*)(As + (wm + i * 16 + l16) * 64 + (((s * 4 + quad) ^ swz) * 8));
#pragma unroll
      for (int j = 0; j < 4; ++j)
        bF[j] = *(const bf16x8*)(Bs + (wn + j * 16 + l16) * 64 + (((s * 4 + quad) ^ swz) * 8));
#pragma unroll
      for (int i = 0; i < 4; ++i)
#pragma unroll
        for (int j = 0; j < 4; ++j)
          acc[i][j] = __builtin_amdgcn_mfma_f32_16x16x32_bf16(aF[i], bF[j], acc[i][j], 0, 0, 0);
    }
  }

  if (MODE == 1 && nBase >= 2048) {
    // V block: write transposed into vt[b][h][d][s]; r=0..3 -> s contiguous
#pragma unroll
    for (int j = 0; j < 4; ++j) {
      const int nG = (int)nBase + wn + j * 16 + l16;
      const float bv = bias[nG];
      const int hd = nG - 2048;
      const int hh = hd >> 6, dd = hd & 63;
#pragma unroll
      for (int i = 0; i < 4; ++i) {
        const int mG0 = (int)mBase + wm + i * 16 + quad * 4;
        const int bb = mG0 >> 11, ss = mG0 & 2047;
        ushort4 o;
        o.x = f2bf(acc[i][j][0] + bv);
        o.y = f2bf(acc[i][j][1] + bv);
        o.z = f2bf(acc[i][j][2] + bv);
        o.w = f2bf(acc[i][j][3] + bv);
        *(ushort4*)(vt + (((long)(bb * NHEAD + hh)) * HDIM + dd) * SLEN + ss) = o;
      }
    }
  } else {
#pragma unroll
    for (int j = 0; j < 4; ++j) {
      const long nG = nBase + wn + j * 16 + l16;
      const float bv = bias[nG];
#pragma unroll
      for (int i = 0; i < 4; ++i)
#pragma unroll
        for (int r = 0; r < 4; ++r) {
          const long mG = mBase + wm + i * 16 + quad * 4 + r;
          const float v = acc[i][j][r] + bv;
          if (MODE == 1) ((unsigned short*)Cout)[mG * ldc + nG] = f2bf(v);
          else           ((float*)Cout)[mG * ldc + nG] = v;
        }
    }
  }
}

// Banded-causal flash attention, S^T orientation, batched softmax.
// 128-query blocks (512 thr, 8 waves). qk: [B*S][2048] bf16 (Q|K),
// vT: [B*H][64][2048]. K and V staged in XOR-swizzled LDS (GEMM-proven
// conflict-free geometry: 128B-multiple row stride + 16B-chunk XOR).
__global__ __launch_bounds__(512, 4) void local_attn(
    const unsigned short* __restrict__ qk,
    const unsigned short* __restrict__ vT,
    unsigned short* __restrict__ outw)
{
  const int qb = blockIdx.x;   // 128-query tile
  const int h  = blockIdx.y;
  const int b  = blockIdx.z;
  const int tid = threadIdx.x;
  const int wave = tid >> 6, lane = tid & 63;
  const int quad = lane >> 4, l16 = lane & 15;

  __shared__ unsigned short Klds[256 * 64];   // [key][chunk ^ (key&7)]
  __shared__ unsigned short Vlds[64 * 256];   // [d][chunk ^ (d&7)] along key

  const int kwin0 = qb * 128 - WINSZ;         // global key of local key 0

  // --- K staging via global_load_lds (swizzled, clamped rows) ---
  {
    const int kr = lane >> 3, kc = lane & 7;
    const long colOff = 1024 + h * HDIM + ((kc ^ kr) * 8);
#pragma unroll
    for (int t = 0; t < 4; ++t) {
      const int u = wave * 4 + t;                 // unit of 8 keys (32 units)
      const int sk = max(kwin0 + u * 8 + kr, 0);  // clamp; junk masked later
      const unsigned short* g = qk + (long)(b * SLEN + sk) * 2048 + colOff;
      __builtin_amdgcn_global_load_lds(AS1(g), AS3(Klds + u * 512), 16, 0, 0);
    }
  }
  // --- V^T staging: coalesced reads from vT, XOR-swizzled LDS writes ---
  {
    const unsigned short* vbase = vT + ((long)(b * NHEAD + h)) * HDIM * SLEN;
#pragma unroll
    for (int t = 0; t < 4; ++t) {
      const int c = t * 512 + tid;          // [0, 2048): 64 d x 32 chunks
      const int d = c >> 5, k8 = c & 31;
      const int s0 = max(kwin0 + k8 * 8, 0);
      uint4 v = *(const uint4*)(vbase + (long)d * SLEN + s0);
      *(uint4*)(Vlds + d * 256 + ((k8 ^ (d & 7)) * 8)) = v;
    }
  }

  // Q fragments (B-operand): 16 queries per wave
  const int q0 = qb * 128 + wave * 16;
  const long qrow = (long)(b * SLEN + q0 + l16) * 2048 + h * HDIM;
  const bf16x8 qB0 = *(const bf16x8*)(qk + qrow + quad * 8);
  const bf16x8 qB1 = *(const bf16x8*)(qk + qrow + 32 + quad * 8);

  __syncthreads();

  // --- QK^T (S^T orientation): all 5 x 32 keys ---
  const int lbase = (wave * 16) & ~31;
  const int kx = l16 & 7;
  const int a0 = (quad ^ kx) * 8;
  const int a1 = ((4 + quad) ^ kx) * 8;
  f32x4 sc[5][2];
#pragma unroll
  for (int it = 0; it < 5; ++it) {
    const int l0 = lbase + it * 32;
#pragma unroll
    for (int half = 0; half < 2; ++half) {
      const unsigned short* kr_ = Klds + (l0 + half * 16 + l16) * 64;
      const bf16x8 kA0 = *(const bf16x8*)(kr_ + a0);
      const bf16x8 kA1 = *(const bf16x8*)(kr_ + a1);
      f32x4 s;
#pragma unroll
      for (int r = 0; r < 4; ++r) s[r] = 0.f;
      s = __builtin_amdgcn_mfma_f32_16x16x32_bf16(kA0, qB0, s, 0, 0, 0);
      s = __builtin_amdgcn_mfma_f32_16x16x32_bf16(kA1, qB1, s, 0, 0, 0);
      sc[it][half] = s;   // row = key_local = quad*4+r, col = query = l16
    }
  }

  // --- mask + scale; batched softmax (reduce over quads: 2 shfl steps) ---
  // Valid local keys for query: [qlocal - WINSZ, qlocal], clipped below
  // -kwin0 when staging clamped (qb==0 -> 128).
  const int qlocal = WINSZ + wave * 16 + l16;       // own query, local coords
  const int lo = max(wave * 16 + l16, kwin0 < 0 ? -kwin0 : 0);
  const int kb = lbase + quad * 4;
  float m = -3.0e38f;
#pragma unroll
  for (int it = 0; it < 5; ++it)
#pragma unroll
    for (int half = 0; half < 2; ++half)
#pragma unroll
      for (int r = 0; r < 4; ++r) {
        const int kl = kb + it * 32 + half * 16 + r;
        float v = sc[it][half][r] * 0.125f;
        v = (kl >= lo && kl <= qlocal) ? v : -3.0e38f;
        sc[it][half][r] = v;
        m = fmaxf(m, v);
      }
  m = fmaxf(m, __shfl_xor(m, 16, 64));
  m = fmaxf(m, __shfl_xor(m, 32, 64));

  float lsum = 0.f;
#pragma unroll
  for (int it = 0; it < 5; ++it)
#pragma unroll
    for (int half = 0; half < 2; ++half)
#pragma unroll
      for (int r = 0; r < 4; ++r) {
        const float e = __expf(sc[it][half][r] - m);
        sc[it][half][r] = e;
        lsum += e;
      }
  lsum += __shfl_xor(lsum, 16, 64);
  lsum += __shfl_xor(lsum, 32, 64);
  const float invl = 1.0f / lsum;

  // --- PV: O^T = V^T * P^T; P^T B-frag assembled via shuffles ---
  f32x4 Oacc[4];
#pragma unroll
  for (int dt = 0; dt < 4; ++dt)
#pragma unroll
    for (int r = 0; r < 4; ++r) Oacc[dt][r] = 0.f;

#pragma unroll
  for (int it = 0; it < 5; ++it) {
    const int l0 = lbase + it * 32;
    // pack this lane's 8 P values (4 per half) into bf16 pairs
    const unsigned int u0 = pack_bf(sc[it][0][0], sc[it][0][1]);
    const unsigned int u1 = pack_bf(sc[it][0][2], sc[it][0][3]);
    const unsigned int u2 = pack_bf(sc[it][1][0], sc[it][1][1]);
    const unsigned int u3 = pack_bf(sc[it][1][2], sc[it][1][3]);
    // gather B-frag: lane needs keys quad*8 + [0..7] of query l16
    unsigned int breg[4];
#pragma unroll
    for (int r = 0; r < 4; ++r) {
      const int srcl = ((quad & 1) * 2 + (r >> 1)) * 16 + l16;
      const unsigned int ga = __shfl((int)((r & 1) ? u1 : u0), srcl, 64);
      const unsigned int gb = __shfl((int)((r & 1) ? u3 : u2), srcl, 64);
      breg[r] = (quad >> 1) ? gb : ga;
    }
    union { unsigned int u[4]; bf16x8 v; } pB;
    pB.u[0] = breg[0]; pB.u[1] = breg[1]; pB.u[2] = breg[2]; pB.u[3] = breg[3];

    const int chBase = (l0 >> 3);                 // multiple of 4
#pragma unroll
    for (int dt = 0; dt < 4; ++dt) {
      const int ch = (chBase + quad) ^ kx;        // kx = l16&7 = d&7
      const bf16x8 vA = *(const bf16x8*)(Vlds + (dt * 16 + l16) * 256 + ch * 8);
      Oacc[dt] = __builtin_amdgcn_mfma_f32_16x16x32_bf16(vA, pB.v, Oacc[dt], 0, 0, 0);
    }
  }

  // --- epilogue: O^T C-layout; r=0..3 contiguous -> packed ushort4 stores ---
  const long obase = (long)(b * SLEN + q0 + l16) * EMB + h * HDIM;
#pragma unroll
  for (int dt = 0; dt < 4; ++dt) {
    ushort4 o;
    o.x = f2bf(Oacc[dt][0] * invl);
    o.y = f2bf(Oacc[dt][1] * invl);
    o.z = f2bf(Oacc[dt][2] * invl);
    o.w = f2bf(Oacc[dt][3] * invl);
    *(ushort4*)(outw + obase + dt * 16 + quad * 4) = o;
  }
}

extern "C" void kernel_launch(void* const* d_in, const int* in_sizes, int n_in,
                              void* d_out, int out_size, void* d_ws, size_t ws_size,
                              hipStream_t stream) {
  const float* x     = (const float*)d_in[0];
  const float* w_in  = (const float*)d_in[1];
  const float* b_in  = (const float*)d_in[2];
  const float* w_out = (const float*)d_in[3];
  const float* b_out = (const float*)d_in[4];
  float* out = (float*)d_out;

  char* ws = (char*)d_ws;
  unsigned short* xb    = (unsigned short*)(ws + 0);          // 16,777,216
  unsigned short* winb  = (unsigned short*)(ws + 16777216);   //  6,291,456
  unsigned short* woutb = (unsigned short*)(ws + 23068672);   //  2,097,152
  unsigned short* qkb   = (unsigned short*)(ws + 25165824);   // 8192x2048 bf16 = 33,554,432
  unsigned short* attn  = (unsigned short*)(ws + 58720256);   // 16,777,216
  unsigned short* vT    = (unsigned short*)(ws + 75497472);   // 16,777,216  (total 92,274,688)

  // fused converts: dst regions are contiguous (xb|winb|woutb)
  const long ncv = 8388608 + 3145728 + 1048576;               // 12,582,912
  cvt_all<<<(int)(ncv / 1024), 256, 0, stream>>>(x, w_in, w_out, xb);

  // qkv projection: Q,K -> qkb (stride 2048); V -> vT transposed
  gemm_nt<1><<<dim3(3072 / 128, 8192 / 128), 256, 0, stream>>>(
      xb, winb, b_in, (void*)qkb, vT, 8192, 3072, 1024, 2048);

  local_attn<<<dim3(SLEN / 128, NHEAD, 4), 512, 0, stream>>>(qkb, vT, attn);

  gemm_nt<0><<<dim3(1024 / 128, 8192 / 128), 256, 0, stream>>>(
      attn, woutb, b_out, (void*)out, nullptr, 8192, 1024, 1024, 1024);
}